// Round 11
// baseline (597.281 us; speedup 1.0000x reference)
//
#include <hip/hip_runtime.h>
#include <hip/hip_bf16.h>

#ifndef M_PI
#define M_PI 3.14159265358979323846
#endif

#define BN_EPS 1e-5f

// ---------------- workspace layout (float offsets) — identical to rounds 1-10 ----------------
#define OFF_Y1   0ull                      // [b][4c][16^3] bf16
#define OFF_Y2   16777216ull               // [b][16c][8^3] bf16
#define OFF_Y3   25165824ull               // [b][32c][4^3] bf16
#define OFF_Y4   27262976ull               // [b][64c][2^3] fp32
#define OFF_Y5   27787264ull
#define OFF_S    27918336ull
#define OFF_W2G  28442624ull
#define OFF_W3G  28444352ull
#define OFF_W5G  28458176ull
#define OFF_U    28523712ull
#define OFF_SP1  28523776ull
#define OFF_SP2  28524288ull
#define OFF_SP3  28526336ull
#define OFF_SP4  28530432ull
#define OFF_SP5  28538624ull
#define SP_TOTAL 31232
#define OFF_W4G  OFF_Y1                     // aliases dead y1

__device__ __forceinline__ float wred(float v) {
    for (int m = 32; m; m >>= 1) v += __shfl_xor(v, m, 64);
    return v;
}

__device__ __forceinline__ void async_copy16(const void* g, void* l) {
    __builtin_amdgcn_global_load_lds((const __attribute__((address_space(1))) void*)g,
                                     (__attribute__((address_space(3))) void*)l,
                                     16, 0, 0);
}

__device__ __forceinline__ unsigned short f2bf(float f) {
    unsigned int x = __float_as_uint(f);
    unsigned int r = (x + 0x7fffu + ((x >> 16) & 1u)) >> 16;
    return (unsigned short)r;
}
__device__ __forceinline__ float bf2f(unsigned short u) {
    return __uint_as_float(((unsigned int)u) << 16);
}

// ---------------- prep: gather weights + zero stat partials ----------------
__global__ void k_prep_w(const float* __restrict__ W2, const float* __restrict__ W3,
                         const float* __restrict__ W5,
                         float* __restrict__ w2g, float* __restrict__ w3g,
                         float* __restrict__ w5g, float* __restrict__ sp) {
    int idx = blockIdx.x * 256 + threadIdx.x;
    if (idx < 1728) {
        int co = idx & 15; int r = idx >> 4; int tap = r % 27; int ci = r / 27;
        w2g[idx] = W2[(co * 4 + ci) * 27 + tap];
        return;
    }
    idx -= 1728;
    if (idx < 13824) {
        int co = idx & 31; int r = idx >> 5; int tap = r % 27; int ci = r / 27;
        w3g[idx] = W3[(co * 16 + ci) * 27 + tap];
        return;
    }
    idx -= 13824;
    if (idx < 65536) {
        int co = idx & 127; int k = idx >> 7;
        int dx = k & 1, dy = (k >> 1) & 1, dz = (k >> 2) & 1, ci = k >> 3;
        w5g[idx] = W5[(co * 64 + ci) * 27 + (dz + 1) * 9 + (dy + 1) * 3 + (dx + 1)];
        return;
    }
    idx -= 65536;
    if (idx < SP_TOTAL) sp[idx] = 0.f;
}

__global__ void k_prep_w4(const float* __restrict__ W4, float* __restrict__ w4g) {
    int idx = blockIdx.x * 256 + threadIdx.x;
    if (idx < 55296) {
        int co = idx & 63; int r = idx >> 6;
        int tap = r % 27, ci = r / 27;
        w4g[idx] = W4[(co * 32 + ci) * 27 + tap];
    }
}

// ---------------- prep: u = pe_w @ f1_w ----------------
__global__ void k_prep_u(const float* __restrict__ pe_w, const float* __restrict__ pe_b,
                         const float* __restrict__ f1_w, const float* __restrict__ f1_b,
                         float* __restrict__ u) {
    int t = threadIdx.x;
    if (t < 51) {
        float acc = 0.f;
        for (int j = 0; j < 128; j++) acc += pe_w[t * 128 + j] * f1_w[j];
        u[t] = acc;
    } else if (t == 51) {
        float acc = f1_b[0];
        for (int j = 0; j < 128; j++) acc += pe_b[j] * f1_w[j];
        u[51] = acc;
    }
}

// ---------------- PE scores (fast sincos) ----------------
__global__ __launch_bounds__(256) void k_pe(const float* __restrict__ centers,
                                            const float* __restrict__ u,
                                            float* __restrict__ s) {
    __shared__ float us[52];
    int t = threadIdx.x;
    if (t < 52) us[t] = u[t];
    __syncthreads();
    int idx = blockIdx.x * 256 + t;
    float c3[3];
    c3[0] = centers[idx * 3 + 0];
    c3[1] = centers[idx * 3 + 1];
    c3[2] = centers[idx * 3 + 2];
    float acc = us[51] + c3[0] * us[48] + c3[1] * us[49] + c3[2] * us[50];
#pragma unroll
    for (int a = 0; a < 3; a++) {
#pragma unroll
        for (int f = 0; f < 8; f++) {
            float ang = c3[a] * (float)(M_PI * (double)(1 << f));
            float sv, cv;
            __sincosf(ang, &sv, &cv);
            acc += sv * us[a * 8 + f] + cv * us[24 + a * 8 + f];
        }
    }
    s[idx] = acc;
}

// ---------------- conv1: z-marching ring pipeline; y1 bf16 (unchanged) ----------------
__global__ __launch_bounds__(256) void k_c1(const float* __restrict__ vox,
                                            const float* __restrict__ W1,
                                            const float* __restrict__ b1,
                                            unsigned short* __restrict__ y1b,
                                            float* __restrict__ sp1) {
    __shared__ __align__(16) float slab[9 * 1024];
    __shared__ __align__(16) float wl[112];
    __shared__ float red2[32];
    int bid = blockIdx.x;
    int b = bid >> 1, q = bid & 1;
    int t = threadIdx.x;
    const float* vb = vox + (size_t)b * 32768;
    int wu = __builtin_amdgcn_readfirstlane(t >> 6);

    if (t < 108) { int tap = t >> 2, co = t & 3; wl[t] = W1[co * 27 + tap]; }
    if (q == 0) ((float4*)slab)[t] = make_float4(0.f, 0.f, 0.f, 0.f);

    int p0 = 16 * q;
    int s0 = q ? 7 : 0;
    {
        int s = s0;
        for (int i = 0; i < 5; i++) {
            int p = p0 - 1 + i;
            if (p >= 0) async_copy16(vb + p * 1024 + t * 4, slab + s * 1024 + wu * 256);
            s++; if (s == 9) s = 0;
        }
    }
    int yo = t >> 4, xo = t & 15;
    int e = 2 * xo;
    int eA = (e >= 2) ? e - 2 : 0;
    float mx0 = xo ? 1.f : 0.f;
    int iyc[3]; float myv[3];
#pragma unroll
    for (int ky = 0; ky < 3; ky++) {
        int iy = 2 * yo + ky - 1;
        myv[ky] = (iy < 0) ? 0.f : 1.f;
        iyc[ky] = (iy < 0) ? 0 : iy;
    }
    float bb0 = b1[0], bb1 = b1[1], bb2 = b1[2], bb3 = b1[3];
    float sums[4] = {0.f, 0.f, 0.f, 0.f}, sqs[4] = {0.f, 0.f, 0.f, 0.f};

    asm volatile("s_waitcnt vmcnt(0)" ::: "memory");
    __syncthreads();

    int s_win = s0;
    for (int j = 0; j < 4; j++) {
        int zq = 4 * q + j;
        if (j < 3) {
            int sp = s_win + 5; if (sp >= 9) sp -= 9;
            for (int i = 0; i < 4; i++) {
                int p = 4 * zq + 4 + i;
                async_copy16(vb + p * 1024 + t * 4, slab + sp * 1024 + wu * 256);
                sp++; if (sp == 9) sp = 0;
            }
        }
        int P[5];
        {
            int s = s_win;
#pragma unroll
            for (int i = 0; i < 5; i++) { P[i] = s * 1024; s++; if (s == 9) s = 0; }
        }
        float a0[4] = {bb0, bb1, bb2, bb3};
        float a1[4] = {bb0, bb1, bb2, bb3};
#pragma unroll
        for (int kz = 0; kz < 3; kz++) {
            const float* pz0 = slab + P[kz];
            const float* pz1 = slab + P[kz + 2];
#pragma unroll
            for (int ky = 0; ky < 3; ky++) {
                int ro = iyc[ky] * 32;
                float2 xa0 = *(const float2*)(pz0 + ro + eA);
                float2 xb0 = *(const float2*)(pz0 + ro + e);
                float2 xa1 = *(const float2*)(pz1 + ro + eA);
                float2 xb1 = *(const float2*)(pz1 + ro + e);
                float m1 = myv[ky], m0 = m1 * mx0;
                const float* wt = wl + (kz * 9 + ky * 3) * 4;
                float4 w0 = *(const float4*)(wt);
                float4 w1 = *(const float4*)(wt + 4);
                float4 w2 = *(const float4*)(wt + 8);
                float v00 = xa0.y * m0, v01 = xb0.x * m1, v02 = xb0.y * m1;
                float v10 = xa1.y * m0, v11 = xb1.x * m1, v12 = xb1.y * m1;
                a0[0] += v00 * w0.x + v01 * w1.x + v02 * w2.x;
                a0[1] += v00 * w0.y + v01 * w1.y + v02 * w2.y;
                a0[2] += v00 * w0.z + v01 * w1.z + v02 * w2.z;
                a0[3] += v00 * w0.w + v01 * w1.w + v02 * w2.w;
                a1[0] += v10 * w0.x + v11 * w1.x + v12 * w2.x;
                a1[1] += v10 * w0.y + v11 * w1.y + v12 * w2.y;
                a1[2] += v10 * w0.z + v11 * w1.z + v12 * w2.z;
                a1[3] += v10 * w0.w + v11 * w1.w + v12 * w2.w;
            }
        }
        size_t base = (size_t)b * 16384 + (size_t)(2 * zq) * 256 + t;
#pragma unroll
        for (int c = 0; c < 4; c++) {
            y1b[base + c * 4096] = f2bf(a0[c]);
            y1b[base + c * 4096 + 256] = f2bf(a1[c]);
            sums[c] += a0[c] + a1[c];
            sqs[c] += a0[c] * a0[c] + a1[c] * a1[c];
        }
        s_win += 4; if (s_win >= 9) s_win -= 9;
        asm volatile("s_waitcnt vmcnt(0)" ::: "memory");
        __syncthreads();
    }
    int lane = t & 63, w = t >> 6;
#pragma unroll
    for (int c = 0; c < 4; c++) { sums[c] = wred(sums[c]); sqs[c] = wred(sqs[c]); }
    if (lane == 0) {
#pragma unroll
        for (int c = 0; c < 4; c++) { red2[w * 8 + c] = sums[c]; red2[w * 8 + 4 + c] = sqs[c]; }
    }
    __syncthreads();
    if (t < 8) {
        int c = t >> 1, isq = t & 1;
        float acc = red2[isq * 4 + c] + red2[8 + isq * 4 + c] +
                    red2[16 + isq * 4 + c] + red2[24 + isq * 4 + c];
        atomicAdd(&sp1[(2 * c + isq) * 64 + (bid & 63)], acc);
    }
}

// ---------------- conv2 v7: waves = co-quarters, 4z x 4co per thread ----------------
// Weight b128 broadcasts halved (432/block); inputs as b32 pair reads (216/wave).
// Staging and LDS layout byte-identical to proven v5.
__global__ __launch_bounds__(256, 4) void k_c2(const unsigned short* __restrict__ y1b,
                                               const float* __restrict__ w2g,
                                               const float* __restrict__ b2,
                                               const float* __restrict__ g1,
                                               const float* __restrict__ be1,
                                               const float* __restrict__ sp1,
                                               unsigned short* __restrict__ y2u,
                                               float* __restrict__ sp2) {
    __shared__ __align__(16) unsigned short slab16[9216];  // [9p][4ci][256] bf16, swizzled
    __shared__ __align__(16) float wl[1728];
    __shared__ float adl[8];
    __shared__ float red[8];
    int t = threadIdx.x;
    int bid = blockIdx.x;
    int b = bid >> 1, q = bid & 1;
    int w = t >> 6, lane = t & 63;
    int wu = __builtin_amdgcn_readfirstlane(w);
    const unsigned short* yb = y1b + (size_t)b * 16384;
    if (q == 0) ((float2*)slab16)[t] = make_float2(0.f, 0.f);   // zero plane 0 (zi=-1)
    {
        int h = wu & 1;
        int ci0 = h * 2 + (lane >> 5);
        int g = lane & 31;
        int gs = g ^ (((g >> 3) & 3) << 1);
        const unsigned short* src0 = yb + ci0 * 4096 + gs * 8;
        int pstart = wu >> 1;
        if (q == 0 && pstart == 0) pstart = 2;
        for (int p = pstart; p < 9; p += 2) {
            int zi = 8 * q - 1 + p;
            async_copy16(src0 + zi * 256, slab16 + p * 1024 + h * 512);
        }
    }
    for (int i = t; i < 1728; i += 256) wl[i] = w2g[i];
    for (int row = w; row < 8; row += 4) {
        float v = wred(sp1[row * 64 + lane]);
        if (lane == 0) red[row] = v;
    }
    __syncthreads();
    if (t < 4) {
        float cnt = 4194304.0f;
        float m = red[2 * t] / cnt;
        float var = red[2 * t + 1] / cnt - m * m;
        float a = g1[t] * rsqrtf(var + BN_EPS);
        adl[t] = a; adl[4 + t] = be1[t] - m * a;
    }
    asm volatile("s_waitcnt vmcnt(0)" ::: "memory");
    __syncthreads();
    int cgo = __builtin_amdgcn_readfirstlane(wu * 4);   // co quarter
    int yo = lane >> 3, xo = lane & 7;
    float my0 = yo ? 1.f : 0.f, mx0 = xo ? 1.f : 0.f;
    float mq = (q == 0) ? 0.f : 1.f;                    // plane 0 mask (zi=-1)
    int yw3[3], sw3[3];
#pragma unroll
    for (int k = 0; k < 3; k++) {
        int yi = 2 * yo + k - 1; int yc = yi < 0 ? 0 : yi;
        yw3[k] = yc * 8;
        sw3[k] = ((yc >> 2) & 3) << 3;
    }
    int xhL = (xo > 0) ? (xo - 1) : 0;
    int xhR = xo;
    float aa[4], dd[4];
#pragma unroll
    for (int c = 0; c < 4; c++) { aa[c] = adl[c]; dd[c] = adl[4 + c]; }
    float acc[4][4];
#pragma unroll
    for (int z = 0; z < 4; z++)
#pragma unroll
        for (int j = 0; j < 4; j++) acc[z][j] = b2[cgo + j];
    for (int ci = 0; ci < 4; ci++) {
        float a = aa[ci], d = dd[ci];
        const unsigned int* base32 = (const unsigned int*)(slab16 + ci * 256);
        const float* wci = wl + ci * 432 + cgo;
#pragma unroll
        for (int ky = 0; ky < 3; ky++) {
            int wLw = (yw3[ky] + xhL) ^ sw3[ky];
            int wRw = (yw3[ky] + xhR) ^ sw3[ky];
            float4 w9[9];
#pragma unroll
            for (int kz = 0; kz < 3; kz++)
#pragma unroll
                for (int kx = 0; kx < 3; kx++)
                    w9[kz * 3 + kx] = *(const float4*)(wci + (kz * 9 + ky * 3 + kx) * 16);
            float m1 = (ky == 0) ? my0 : 1.f;
            float m0 = m1 * mx0;
#pragma unroll
            for (int p = 0; p < 9; p++) {
                const unsigned int* pp = base32 + p * 512;
                unsigned int L = pp[wLw], R = pp[wRw];
                float v0 = __uint_as_float(L & 0xffff0000u);   // kx=0 (x = 2xo-1)
                float v1 = __uint_as_float(R << 16);           // kx=1 (x = 2xo)
                float v2 = __uint_as_float(R & 0xffff0000u);   // kx=2 (x = 2xo+1)
                float pb = (p == 0) ? mq : 1.f;
                float vb0 = fmaxf(a * v0 + d, 0.f) * (m0 * pb);
                float vb1 = fmaxf(a * v1 + d, 0.f) * (m1 * pb);
                float vb2 = fmaxf(a * v2 + d, 0.f) * (m1 * pb);
#pragma unroll
                for (int z = 0; z < 4; z++) {
                    int kz = p - 2 * z;
                    if (kz < 0 || kz > 2) continue;
                    float4 wa = w9[kz * 3 + 0];
                    float4 wb_ = w9[kz * 3 + 1];
                    float4 wc = w9[kz * 3 + 2];
                    acc[z][0] += vb0 * wa.x + vb1 * wb_.x + vb2 * wc.x;
                    acc[z][1] += vb0 * wa.y + vb1 * wb_.y + vb2 * wc.y;
                    acc[z][2] += vb0 * wa.z + vb1 * wb_.z + vb2 * wc.z;
                    acc[z][3] += vb0 * wa.w + vb1 * wb_.w + vb2 * wc.w;
                }
            }
        }
    }
    size_t ob = (size_t)b * 8192 + (size_t)cgo * 512 + (size_t)(4 * q) * 64 + lane;
#pragma unroll
    for (int j = 0; j < 4; j++)
#pragma unroll
        for (int z = 0; z < 4; z++)
            y2u[ob + j * 512 + z * 64] = f2bf(acc[z][j]);
    int slot = bid & 63;
#pragma unroll
    for (int j = 0; j < 4; j++) {
        float s_ = 0.f, q_ = 0.f;
#pragma unroll
        for (int z = 0; z < 4; z++) { s_ += acc[z][j]; q_ += acc[z][j] * acc[z][j]; }
        s_ = wred(s_); q_ = wred(q_);
        if (lane == 0) {
            atomicAdd(&sp2[(2 * (cgo + j)) * 64 + slot], s_);
            atomicAdd(&sp2[(2 * (cgo + j) + 1) * 64 + slot], q_);
        }
    }
}

// ---------------- conv3: bf16 slab (round-10 version, unchanged) ----------------
__global__ __launch_bounds__(256) void k_c3(const unsigned short* __restrict__ y2u,
                                            const float* __restrict__ w3g,
                                            const float* __restrict__ b3,
                                            const float* __restrict__ g2,
                                            const float* __restrict__ be2,
                                            const float* __restrict__ sp2,
                                            unsigned short* __restrict__ y3u,
                                            float* __restrict__ sp3) {
    __shared__ __align__(16) unsigned short in3u[8192];   // 16 KB
    __shared__ float adl[32], red[32];
    int t = threadIdx.x;
    int b = blockIdx.x;
    int w = t >> 6, lane = t & 63;
    int wu = __builtin_amdgcn_readfirstlane(w);
    {
        int zc = lane >> 3;
        int gsrc = (lane & 7) ^ zc;
        const unsigned short* srcb = y2u + (size_t)b * 8192 + zc * 64 + gsrc * 8;
        for (int cq = 0; cq < 4; cq++) {
            int ci = wu * 4 + cq;
            async_copy16(srcb + ci * 512, in3u + ci * 512);
        }
    }
    for (int row = w; row < 32; row += 4) {
        float v = wred(sp2[row * 64 + lane]);
        if (lane == 0) red[row] = v;
    }
    __syncthreads();
    if (t < 16) {
        float cnt = 524288.0f;
        float m = red[2 * t] / cnt;
        float var = red[2 * t + 1] / cnt - m * m;
        float a = g2[t] * rsqrtf(var + BN_EPS);
        adl[t] = a; adl[16 + t] = be2[t] - m * a;
    }
    asm volatile("s_waitcnt vmcnt(0)" ::: "memory");
    __syncthreads();
    int px = lane & 3, py = (lane >> 2) & 3, pz = lane >> 4;
    float mz0 = pz ? 1.f : 0.f, my0 = py ? 1.f : 0.f, mx0 = px ? 1.f : 0.f;
    int zo3[3], zx3[3], yw3[3], xh3[3], xp3[3];
#pragma unroll
    for (int k = 0; k < 3; k++) {
        int zi = 2 * pz + k - 1; int zc = zi < 0 ? 0 : zi;
        zo3[k] = zc * 64; zx3[k] = (zc & 7) << 2;
        int yi = 2 * py + k - 1; int yc = yi < 0 ? 0 : yi;
        yw3[k] = yc * 4;
        int xi = 2 * px + k - 1; int xv = xi < 0 ? 0 : xi;
        xh3[k] = xv >> 1; xp3[k] = xv & 1;
    }
    int coh = wu & 1, cih = wu >> 1;
    int cgo = coh * 16;
    float acc[16];
#pragma unroll
    for (int c = 0; c < 16; c++) acc[c] = 0.f;
    for (int cii = 0; cii < 8; cii++) {
        int ci = cih * 8 + cii;
        float a = adl[ci], d = adl[16 + ci];
        const unsigned short* base = in3u + ci * 512;
        const float* wci = w3g + ci * 864 + cgo;
#pragma unroll
        for (int kz = 0; kz < 3; kz++) {
            int zo = zo3[kz], zx = zx3[kz];
#pragma unroll
            for (int ky = 0; ky < 3; ky++) {
                int yw = yw3[ky];
#pragma unroll
                for (int kx = 0; kx < 3; kx++) {
                    int idx = zo + ((((yw + xh3[kx]) ^ zx) << 1) | xp3[kx]);
                    float v = bf2f(base[idx]);
                    float vb = fmaxf(a * v + d, 0.f);
                    if (kz == 0) vb *= mz0;
                    if (ky == 0) vb *= my0;
                    if (kx == 0) vb *= mx0;
                    const float* wr = wci + (kz * 9 + ky * 3 + kx) * 32;
#pragma unroll
                    for (int c = 0; c < 16; c++) acc[c] += vb * wr[c];
                }
            }
        }
    }
    __syncthreads();
    float* sc = (float*)in3u;
    if (wu >= 2) {
        float* pp = sc + (wu & 1) * 1280 + lane * 20;
#pragma unroll
        for (int c4 = 0; c4 < 4; c4++)
            *(float4*)(pp + c4 * 4) = make_float4(acc[c4*4], acc[c4*4+1], acc[c4*4+2], acc[c4*4+3]);
    }
    __syncthreads();
    if (wu < 2) {
        const float* pp = sc + wu * 1280 + lane * 20;
#pragma unroll
        for (int c = 0; c < 16; c++) acc[c] += pp[c] + b3[cgo + c];
        size_t ob = (size_t)b * 2048 + lane;
#pragma unroll
        for (int c = 0; c < 16; c++) y3u[ob + (size_t)(cgo + c) * 64] = f2bf(acc[c]);
        int slot = b & 63;
#pragma unroll
        for (int c = 0; c < 16; c++) {
            float s_ = wred(acc[c]), q_ = wred(acc[c] * acc[c]);
            if (lane == 0) {
                atomicAdd(&sp3[(2 * (cgo + c)) * 64 + slot], s_);
                atomicAdd(&sp3[(2 * (cgo + c) + 1) * 64 + slot], q_);
            }
        }
    }
}

// ---------------- conv4: bf16 slab (round-10 version, unchanged) ----------------
__global__ __launch_bounds__(256) void k_c4(const unsigned short* __restrict__ y3u,
                                            const float* __restrict__ w4g,
                                            const float* __restrict__ b4,
                                            const float* __restrict__ g3,
                                            const float* __restrict__ be3,
                                            const float* __restrict__ sp3,
                                            float* __restrict__ y4,
                                            float* __restrict__ sp4) {
    __shared__ __align__(16) unsigned short in4u[8 * 2056];
    __shared__ float adb[64], red[64];
    int t = threadIdx.x;
    int bid = blockIdx.x;
    int bq = bid >> 2, coq = bid & 3;
    int w = t >> 6, lane = t & 63;
    int wu = __builtin_amdgcn_readfirstlane(w);
#pragma unroll
    for (int h = 0; h < 2; h++) {
        int bs2 = wu * 2 + h;
        const unsigned short* src = y3u + (size_t)(bq * 8 + bs2) * 2048 + lane * 8;
        for (int j = 0; j < 4; j++)
            async_copy16(src + j * 512, in4u + bs2 * 2056 + j * 512);
    }
    for (int row = w; row < 64; row += 4) {
        float v = wred(sp3[row * 64 + lane]);
        if (lane == 0) red[row] = v;
    }
    __syncthreads();
    if (t < 32) {
        float cnt = 65536.0f;
        float m = red[2 * t] / cnt;
        float var = red[2 * t + 1] / cnt - m * m;
        float a = g3[t] * rsqrtf(var + BN_EPS);
        adb[t] = a; adb[32 + t] = be3[t] - m * a;
    }
    asm volatile("s_waitcnt vmcnt(0)" ::: "memory");
    __syncthreads();
    int bs = lane >> 3, pos = lane & 7;
    int pz = pos >> 2, py = (pos >> 1) & 1, px = pos & 1;
    int z0 = 2 * pz - 1; if (z0 < 0) z0 = 0;
    int y0 = 2 * py - 1; if (y0 < 0) y0 = 0;
    int x0 = 2 * px - 1; if (x0 < 0) x0 = 0;
    int zo_[3] = {z0 * 16, 2 * pz * 16, (2 * pz + 1) * 16};
    int yo_[3] = {y0 * 4, 2 * py * 4, (2 * py + 1) * 4};
    int xo_[3] = {x0, 2 * px, 2 * px + 1};
    float mz = pz ? 1.f : 0.f, my = py ? 1.f : 0.f, mx = px ? 1.f : 0.f;
    float acc[16];
#pragma unroll
    for (int c = 0; c < 16; c++) acc[c] = 0.f;
    const unsigned short* inb = in4u + bs * 2056;
    for (int cii = 0; cii < 8; cii++) {
        int ci = wu * 8 + cii;
        float a = adb[ci], d = adb[32 + ci];
        const unsigned short* inc = inb + ci * 64;
        const float* wcb = w4g + ci * 1728 + coq * 16;
#pragma unroll
        for (int kz = 0; kz < 3; kz++)
#pragma unroll
            for (int ky = 0; ky < 3; ky++)
#pragma unroll
                for (int kx = 0; kx < 3; kx++) {
                    float v = bf2f(inc[zo_[kz] + yo_[ky] + xo_[kx]]);
                    float vb = fmaxf(a * v + d, 0.f);
                    if (kz == 0) vb *= mz;
                    if (ky == 0) vb *= my;
                    if (kx == 0) vb *= mx;
                    const float* wr = wcb + (kz * 9 + ky * 3 + kx) * 64;
#pragma unroll
                    for (int c = 0; c < 16; c++) acc[c] += vb * wr[c];
                }
    }
    __syncthreads();
    float* sc = (float*)in4u;
    if (wu > 0) {
        float* pp = sc + (wu - 1) * 1280 + lane * 20;
#pragma unroll
        for (int c4 = 0; c4 < 4; c4++)
            *(float4*)(pp + c4 * 4) = make_float4(acc[c4*4], acc[c4*4+1], acc[c4*4+2], acc[c4*4+3]);
    }
    __syncthreads();
    if (wu == 0) {
#pragma unroll
        for (int p = 0; p < 3; p++) {
            const float* pp = sc + p * 1280 + lane * 20;
#pragma unroll
            for (int c = 0; c < 16; c++) acc[c] += pp[c];
        }
        int bfull = bq * 8 + bs;
        size_t ob = (size_t)bfull * 512 + pos;
        int slot = bid & 63;
#pragma unroll
        for (int c = 0; c < 16; c++) {
            float vv = acc[c] + b4[coq * 16 + c];
            y4[ob + (size_t)(coq * 16 + c) * 8] = vv;
            acc[c] = vv;
        }
#pragma unroll
        for (int c = 0; c < 16; c++) {
            float s_ = wred(acc[c]), q_ = wred(acc[c] * acc[c]);
            if (lane == 0) {
                atomicAdd(&sp4[(2 * (coq * 16 + c)) * 64 + slot], s_);
                atomicAdd(&sp4[(2 * (coq * 16 + c) + 1) * 64 + slot], q_);
            }
        }
    }
}

// ---------------- conv5 as GEMM (unchanged) ----------------
__global__ __launch_bounds__(512) void k_c5(const float* __restrict__ y4,
                                            const float* __restrict__ w5g,
                                            const float* __restrict__ b5,
                                            const float* __restrict__ g4,
                                            const float* __restrict__ be4,
                                            const float* __restrict__ sp4,
                                            float* __restrict__ y5,
                                            float* __restrict__ sp5) {
    __shared__ __align__(16) float A[2048];
    __shared__ float P[512];
    __shared__ float ad[128], red[128];
    int t = threadIdx.x;
    int bq = blockIdx.x;
    int w = t >> 6, lane = t & 63;
    for (int row = w; row < 128; row += 8) {
        float v = wred(sp4[row * 64 + lane]);
        if (lane == 0) red[row] = v;
    }
    __syncthreads();
    if (t < 64) {
        float cnt = 8192.0f;
        float m = red[2 * t] / cnt;
        float var = red[2 * t + 1] / cnt - m * m;
        float a = g4[t] * rsqrtf(var + BN_EPS);
        ad[t] = a; ad[64 + t] = be4[t] - m * a;
    }
    __syncthreads();
    {
        int bs = t >> 7, k0 = (t & 127) << 2;
        float4 vv = *(const float4*)(y4 + (size_t)(bq * 4 + bs) * 512 + k0);
        int ci = k0 >> 3;
        float a = ad[ci], d = ad[64 + ci];
        float4 o;
        o.x = fmaxf(a * vv.x + d, 0.f);
        o.y = fmaxf(a * vv.y + d, 0.f);
        o.z = fmaxf(a * vv.z + d, 0.f);
        o.w = fmaxf(a * vv.w + d, 0.f);
        *(float4*)(A + bs * 512 + k0) = o;
    }
    __syncthreads();
    int bs = w & 3, kh = w >> 2;
    float acc0 = 0.f, acc1 = 0.f;
    const float* Ab = A + bs * 512 + kh * 256;
    const float* wp = w5g + kh * 32768 + lane * 2;
#pragma unroll 8
    for (int k = 0; k < 256; k++) {
        float2 wv = *(const float2*)(wp + k * 128);
        float av = Ab[k];
        acc0 += av * wv.x;
        acc1 += av * wv.y;
    }
    if (kh == 0) {
        P[bs * 128 + lane * 2] = acc0;
        P[bs * 128 + lane * 2 + 1] = acc1;
    }
    __syncthreads();
    if (kh == 1) {
        float f0 = acc0 + P[bs * 128 + lane * 2] + b5[lane * 2];
        float f1 = acc1 + P[bs * 128 + lane * 2 + 1] + b5[lane * 2 + 1];
        *(float2*)(y5 + (size_t)(bq * 4 + bs) * 128 + lane * 2) = make_float2(f0, f1);
        P[bs * 128 + lane * 2] = f0;
        P[bs * 128 + lane * 2 + 1] = f1;
    }
    __syncthreads();
    if (t < 128) {
        float s = 0.f, q = 0.f;
        for (int bb = 0; bb < 4; bb++) {
            float vv = P[bb * 128 + t];
            s += vv; q += vv * vv;
        }
        int slot = bq & 63;
        atomicAdd(&sp5[(2 * t) * 64 + slot], s);
        atomicAdd(&sp5[(2 * t + 1) * 64 + slot], q);
    }
}

// ---------------- final (unchanged) ----------------
__global__ __launch_bounds__(512) void k_f2(const float* __restrict__ s,
                                            const float* __restrict__ f2w,
                                            const float* __restrict__ f2b,
                                            const float* __restrict__ g5,
                                            const float* __restrict__ be5,
                                            const float* __restrict__ sp5,
                                            const float* __restrict__ y5,
                                            float* __restrict__ out) {
    __shared__ __align__(16) float A[2048];
    __shared__ float P[512];
    __shared__ float ad[256], red[256];
    int t = threadIdx.x;
    int bq = blockIdx.x;
    int w = t >> 6, lane = t & 63;
    for (int row = w; row < 256; row += 8) {
        float v = wred(sp5[row * 64 + lane]);
        if (lane == 0) red[row] = v;
    }
    __syncthreads();
    if (t < 128) {
        float cnt = 1024.0f;
        float m = red[2 * t] / cnt;
        float var = red[2 * t + 1] / cnt - m * m;
        float a = g5[t] * rsqrtf(var + BN_EPS);
        ad[t] = a; ad[128 + t] = be5[t] - m * a;
    }
    {
        int bs = t >> 7, k0 = (t & 127) << 2;
        float4 vv = *(const float4*)(s + (size_t)(bq * 4 + bs) * 512 + k0);
        *(float4*)(A + bs * 512 + k0) = vv;
    }
    __syncthreads();
    int bs = w & 3, kh = w >> 2;
    float acc0 = 0.f, acc1 = 0.f;
    const float* Ab = A + bs * 512 + kh * 256;
    const float* wp = f2w + kh * 32768 + lane * 2;
#pragma unroll 8
    for (int k = 0; k < 256; k++) {
        float2 wv = *(const float2*)(wp + k * 128);
        float av = Ab[k];
        acc0 += av * wv.x;
        acc1 += av * wv.y;
    }
    if (kh == 0) {
        P[bs * 128 + lane * 2] = acc0;
        P[bs * 128 + lane * 2 + 1] = acc1;
    }
    __syncthreads();
    if (kh == 1) {
        int b = bq * 4 + bs;
        int co = lane * 2;
        float2 vy = *(const float2*)(y5 + (size_t)b * 128 + co);
        float f0 = acc0 + P[bs * 128 + co] + f2b[co] +
                   fmaxf(ad[co] * vy.x + ad[128 + co], 0.f);
        float f1 = acc1 + P[bs * 128 + co + 1] + f2b[co + 1] +
                   fmaxf(ad[co + 1] * vy.y + ad[128 + co + 1], 0.f);
        *(float2*)(out + (size_t)b * 128 + co) = make_float2(f0, f1);
    }
}

extern "C" void kernel_launch(void* const* d_in, const int* in_sizes, int n_in,
                              void* d_out, int out_size, void* d_ws, size_t ws_size,
                              hipStream_t stream) {
    const float* vox     = (const float*)d_in[0];
    const float* centers = (const float*)d_in[1];
    const float* W1   = (const float*)d_in[2];
    const float* b1   = (const float*)d_in[3];
    const float* g1   = (const float*)d_in[4];
    const float* be1  = (const float*)d_in[5];
    const float* W2   = (const float*)d_in[6];
    const float* b2   = (const float*)d_in[7];
    const float* g2   = (const float*)d_in[8];
    const float* be2  = (const float*)d_in[9];
    const float* W3   = (const float*)d_in[10];
    const float* b3   = (const float*)d_in[11];
    const float* g3   = (const float*)d_in[12];
    const float* be3  = (const float*)d_in[13];
    const float* W4   = (const float*)d_in[14];
    const float* b4   = (const float*)d_in[15];
    const float* g4   = (const float*)d_in[16];
    const float* be4  = (const float*)d_in[17];
    const float* W5   = (const float*)d_in[18];
    const float* b5   = (const float*)d_in[19];
    const float* g5   = (const float*)d_in[20];
    const float* be5  = (const float*)d_in[21];
    const float* pe_w = (const float*)d_in[22];
    const float* pe_b = (const float*)d_in[23];
    const float* f1_w = (const float*)d_in[24];
    const float* f1_b = (const float*)d_in[25];
    const float* f2_w = (const float*)d_in[26];
    const float* f2_b = (const float*)d_in[27];

    float* ws  = (float*)d_ws;
    unsigned short* y1b = (unsigned short*)(ws + OFF_Y1);
    unsigned short* y2u = (unsigned short*)(ws + OFF_Y2);
    unsigned short* y3u = (unsigned short*)(ws + OFF_Y3);
    float* y4  = ws + OFF_Y4;
    float* y5  = ws + OFF_Y5;
    float* s   = ws + OFF_S;
    float* w2g = ws + OFF_W2G;
    float* w3g = ws + OFF_W3G;
    float* w4g = ws + OFF_W4G;
    float* w5g = ws + OFF_W5G;
    float* u   = ws + OFF_U;
    float* sp1 = ws + OFF_SP1;
    float* sp2 = ws + OFF_SP2;
    float* sp3 = ws + OFF_SP3;
    float* sp4 = ws + OFF_SP4;
    float* sp5 = ws + OFF_SP5;

    k_prep_w<<<439, 256, 0, stream>>>(W2, W3, W5, w2g, w3g, w5g, sp1);
    k_prep_u<<<1, 64, 0, stream>>>(pe_w, pe_b, f1_w, f1_b, u);
    k_pe<<<2048, 256, 0, stream>>>(centers, u, s);
    k_c1<<<2048, 256, 0, stream>>>(vox, W1, b1, y1b, sp1);
    k_c2<<<2048, 256, 0, stream>>>(y1b, w2g, b2, g1, be1, sp1, y2u, sp2);
    k_prep_w4<<<216, 256, 0, stream>>>(W4, w4g);
    k_c3<<<1024, 256, 0, stream>>>(y2u, w3g, b3, g2, be2, sp2, y3u, sp3);
    k_c4<<<512, 256, 0, stream>>>(y3u, w4g, b4, g3, be3, sp3, y4, sp4);
    k_c5<<<256, 512, 0, stream>>>(y4, w5g, b5, g4, be4, sp4, y5, sp5);
    k_f2<<<256, 512, 0, stream>>>(s, f2_w, f2_b, g5, be5, sp5, y5, (float*)d_out);
}

// Round 12
// 254.024 us; speedup vs baseline: 2.3513x; 2.3513x over previous
//
#include <hip/hip_runtime.h>
#include <hip/hip_bf16.h>

#ifndef M_PI
#define M_PI 3.14159265358979323846
#endif

#define BN_EPS 1e-5f

// ---------------- workspace layout (float offsets) — identical to rounds 1-11 ----------------
#define OFF_Y1   0ull                      // [b][4c][16^3] bf16 (region sized for fp32)
#define OFF_Y2   16777216ull               // [b][16c][8^3] fp32
#define OFF_Y3   25165824ull               // [b][32c][4^3] fp32
#define OFF_Y4   27262976ull               // [b][64c][2^3] fp32
#define OFF_Y5   27787264ull
#define OFF_S    27918336ull
#define OFF_W2G  28442624ull
#define OFF_W3G  28444352ull
#define OFF_W5G  28458176ull
#define OFF_U    28523712ull
#define OFF_SP1  28523776ull
#define OFF_SP2  28524288ull
#define OFF_SP3  28526336ull
#define OFF_SP4  28530432ull
#define OFF_SP5  28538624ull
#define SP_TOTAL 31232
#define OFF_W4G  OFF_Y1                     // aliases dead y1

__device__ __forceinline__ float wred(float v) {
    for (int m = 32; m; m >>= 1) v += __shfl_xor(v, m, 64);
    return v;
}

// async global->LDS, 16B per lane; lds base must be wave-uniform
__device__ __forceinline__ void async_copy16(const void* g, void* l) {
    __builtin_amdgcn_global_load_lds((const __attribute__((address_space(1))) void*)g,
                                     (__attribute__((address_space(3))) void*)l,
                                     16, 0, 0);
}

// fp32 -> bf16 RNE
__device__ __forceinline__ unsigned short f2bf(float f) {
    unsigned int x = __float_as_uint(f);
    unsigned int r = (x + 0x7fffu + ((x >> 16) & 1u)) >> 16;
    return (unsigned short)r;
}
__device__ __forceinline__ float bf2f(unsigned short u) {
    return __uint_as_float(((unsigned int)u) << 16);
}

// ---------------- prep: gather weights + zero stat partials ----------------
__global__ void k_prep_w(const float* __restrict__ W2, const float* __restrict__ W3,
                         const float* __restrict__ W5,
                         float* __restrict__ w2g, float* __restrict__ w3g,
                         float* __restrict__ w5g, float* __restrict__ sp) {
    int idx = blockIdx.x * 256 + threadIdx.x;
    if (idx < 1728) {
        int co = idx & 15; int r = idx >> 4; int tap = r % 27; int ci = r / 27;
        w2g[idx] = W2[(co * 4 + ci) * 27 + tap];
        return;
    }
    idx -= 1728;
    if (idx < 13824) {
        int co = idx & 31; int r = idx >> 5; int tap = r % 27; int ci = r / 27;
        w3g[idx] = W3[(co * 16 + ci) * 27 + tap];
        return;
    }
    idx -= 13824;
    if (idx < 65536) {
        int co = idx & 127; int k = idx >> 7;
        int dx = k & 1, dy = (k >> 1) & 1, dz = (k >> 2) & 1, ci = k >> 3;
        w5g[idx] = W5[(co * 64 + ci) * 27 + (dz + 1) * 9 + (dy + 1) * 3 + (dx + 1)];
        return;
    }
    idx -= 65536;
    if (idx < SP_TOTAL) sp[idx] = 0.f;
}

__global__ void k_prep_w4(const float* __restrict__ W4, float* __restrict__ w4g) {
    int idx = blockIdx.x * 256 + threadIdx.x;
    if (idx < 55296) {
        int co = idx & 63; int r = idx >> 6;
        int tap = r % 27, ci = r / 27;
        w4g[idx] = W4[(co * 32 + ci) * 27 + tap];
    }
}

// ---------------- prep: u = pe_w @ f1_w ----------------
__global__ void k_prep_u(const float* __restrict__ pe_w, const float* __restrict__ pe_b,
                         const float* __restrict__ f1_w, const float* __restrict__ f1_b,
                         float* __restrict__ u) {
    int t = threadIdx.x;
    if (t < 51) {
        float acc = 0.f;
        for (int j = 0; j < 128; j++) acc += pe_w[t * 128 + j] * f1_w[j];
        u[t] = acc;
    } else if (t == 51) {
        float acc = f1_b[0];
        for (int j = 0; j < 128; j++) acc += pe_b[j] * f1_w[j];
        u[51] = acc;
    }
}

// ---------------- PE scores (fast sincos — validated round 11) ----------------
__global__ __launch_bounds__(256) void k_pe(const float* __restrict__ centers,
                                            const float* __restrict__ u,
                                            float* __restrict__ s) {
    __shared__ float us[52];
    int t = threadIdx.x;
    if (t < 52) us[t] = u[t];
    __syncthreads();
    int idx = blockIdx.x * 256 + t;
    float c3[3];
    c3[0] = centers[idx * 3 + 0];
    c3[1] = centers[idx * 3 + 1];
    c3[2] = centers[idx * 3 + 2];
    float acc = us[51] + c3[0] * us[48] + c3[1] * us[49] + c3[2] * us[50];
#pragma unroll
    for (int a = 0; a < 3; a++) {
#pragma unroll
        for (int f = 0; f < 8; f++) {
            float ang = c3[a] * (float)(M_PI * (double)(1 << f));
            float sv, cv;
            __sincosf(ang, &sv, &cv);
            acc += sv * us[a * 8 + f] + cv * us[24 + a * 8 + f];
        }
    }
    s[idx] = acc;
}

// ---------------- conv1: z-marching ring pipeline; y1 written as bf16 ----------------
__global__ __launch_bounds__(256) void k_c1(const float* __restrict__ vox,
                                            const float* __restrict__ W1,
                                            const float* __restrict__ b1,
                                            unsigned short* __restrict__ y1b,
                                            float* __restrict__ sp1) {
    __shared__ __align__(16) float slab[9 * 1024];
    __shared__ __align__(16) float wl[112];
    __shared__ float red2[32];
    int bid = blockIdx.x;
    int b = bid >> 1, q = bid & 1;
    int t = threadIdx.x;
    const float* vb = vox + (size_t)b * 32768;
    int wu = __builtin_amdgcn_readfirstlane(t >> 6);

    if (t < 108) { int tap = t >> 2, co = t & 3; wl[t] = W1[co * 27 + tap]; }
    if (q == 0) ((float4*)slab)[t] = make_float4(0.f, 0.f, 0.f, 0.f);

    int p0 = 16 * q;
    int s0 = q ? 7 : 0;
    {
        int s = s0;
        for (int i = 0; i < 5; i++) {
            int p = p0 - 1 + i;
            if (p >= 0) async_copy16(vb + p * 1024 + t * 4, slab + s * 1024 + wu * 256);
            s++; if (s == 9) s = 0;
        }
    }
    int yo = t >> 4, xo = t & 15;
    int e = 2 * xo;
    int eA = (e >= 2) ? e - 2 : 0;
    float mx0 = xo ? 1.f : 0.f;
    int iyc[3]; float myv[3];
#pragma unroll
    for (int ky = 0; ky < 3; ky++) {
        int iy = 2 * yo + ky - 1;
        myv[ky] = (iy < 0) ? 0.f : 1.f;
        iyc[ky] = (iy < 0) ? 0 : iy;
    }
    float bb0 = b1[0], bb1 = b1[1], bb2 = b1[2], bb3 = b1[3];
    float sums[4] = {0.f, 0.f, 0.f, 0.f}, sqs[4] = {0.f, 0.f, 0.f, 0.f};

    asm volatile("s_waitcnt vmcnt(0)" ::: "memory");
    __syncthreads();

    int s_win = s0;
    for (int j = 0; j < 4; j++) {
        int zq = 4 * q + j;
        if (j < 3) {
            int sp = s_win + 5; if (sp >= 9) sp -= 9;
            for (int i = 0; i < 4; i++) {
                int p = 4 * zq + 4 + i;
                async_copy16(vb + p * 1024 + t * 4, slab + sp * 1024 + wu * 256);
                sp++; if (sp == 9) sp = 0;
            }
        }
        int P[5];
        {
            int s = s_win;
#pragma unroll
            for (int i = 0; i < 5; i++) { P[i] = s * 1024; s++; if (s == 9) s = 0; }
        }
        float a0[4] = {bb0, bb1, bb2, bb3};
        float a1[4] = {bb0, bb1, bb2, bb3};
#pragma unroll
        for (int kz = 0; kz < 3; kz++) {
            const float* pz0 = slab + P[kz];
            const float* pz1 = slab + P[kz + 2];
#pragma unroll
            for (int ky = 0; ky < 3; ky++) {
                int ro = iyc[ky] * 32;
                float2 xa0 = *(const float2*)(pz0 + ro + eA);
                float2 xb0 = *(const float2*)(pz0 + ro + e);
                float2 xa1 = *(const float2*)(pz1 + ro + eA);
                float2 xb1 = *(const float2*)(pz1 + ro + e);
                float m1 = myv[ky], m0 = m1 * mx0;
                const float* wt = wl + (kz * 9 + ky * 3) * 4;
                float4 w0 = *(const float4*)(wt);
                float4 w1 = *(const float4*)(wt + 4);
                float4 w2 = *(const float4*)(wt + 8);
                float v00 = xa0.y * m0, v01 = xb0.x * m1, v02 = xb0.y * m1;
                float v10 = xa1.y * m0, v11 = xb1.x * m1, v12 = xb1.y * m1;
                a0[0] += v00 * w0.x + v01 * w1.x + v02 * w2.x;
                a0[1] += v00 * w0.y + v01 * w1.y + v02 * w2.y;
                a0[2] += v00 * w0.z + v01 * w1.z + v02 * w2.z;
                a0[3] += v00 * w0.w + v01 * w1.w + v02 * w2.w;
                a1[0] += v10 * w0.x + v11 * w1.x + v12 * w2.x;
                a1[1] += v10 * w0.y + v11 * w1.y + v12 * w2.y;
                a1[2] += v10 * w0.z + v11 * w1.z + v12 * w2.z;
                a1[3] += v10 * w0.w + v11 * w1.w + v12 * w2.w;
            }
        }
        size_t base = (size_t)b * 16384 + (size_t)(2 * zq) * 256 + t;
#pragma unroll
        for (int c = 0; c < 4; c++) {
            y1b[base + c * 4096] = f2bf(a0[c]);
            y1b[base + c * 4096 + 256] = f2bf(a1[c]);
            sums[c] += a0[c] + a1[c];
            sqs[c] += a0[c] * a0[c] + a1[c] * a1[c];
        }
        s_win += 4; if (s_win >= 9) s_win -= 9;
        asm volatile("s_waitcnt vmcnt(0)" ::: "memory");
        __syncthreads();
    }
    int lane = t & 63, w = t >> 6;
#pragma unroll
    for (int c = 0; c < 4; c++) { sums[c] = wred(sums[c]); sqs[c] = wred(sqs[c]); }
    if (lane == 0) {
#pragma unroll
        for (int c = 0; c < 4; c++) { red2[w * 8 + c] = sums[c]; red2[w * 8 + 4 + c] = sqs[c]; }
    }
    __syncthreads();
    if (t < 8) {
        int c = t >> 1, isq = t & 1;
        float acc = red2[isq * 4 + c] + red2[8 + isq * 4 + c] +
                    red2[16 + isq * 4 + c] + red2[24 + isq * 4 + c];
        atomicAdd(&sp1[(2 * c + isq) * 64 + (bid & 63)], acc);
    }
}

// ---------------- conv2 v5 (round-9 proven): bf16 input slab; y2 fp32 out ----------------
__global__ __launch_bounds__(256) void k_c2(const unsigned short* __restrict__ y1b,
                                            const float* __restrict__ w2g,
                                            const float* __restrict__ b2,
                                            const float* __restrict__ g1,
                                            const float* __restrict__ be1,
                                            const float* __restrict__ sp1,
                                            float* __restrict__ y2,
                                            float* __restrict__ sp2) {
    __shared__ __align__(16) unsigned short slab16[9216];  // [9p][4ci][256] bf16, swizzled
    __shared__ __align__(16) float wl[1728];
    __shared__ float adl[8];
    __shared__ float red[8];
    int t = threadIdx.x;
    int bid = blockIdx.x;
    int b = bid >> 1, q = bid & 1;
    int w = t >> 6, lane = t & 63;
    int wu = __builtin_amdgcn_readfirstlane(w);
    const unsigned short* yb = y1b + (size_t)b * 16384;
    if (q == 0) ((float2*)slab16)[t] = make_float2(0.f, 0.f);
    {
        int h = wu & 1;
        int ci0 = h * 2 + (lane >> 5);
        int g = lane & 31;
        int gs = g ^ (((g >> 3) & 3) << 1);
        const unsigned short* src0 = yb + ci0 * 4096 + gs * 8;
        int pstart = wu >> 1;
        if (q == 0 && pstart == 0) pstart = 2;
        for (int p = pstart; p < 9; p += 2) {
            int zi = 8 * q - 1 + p;
            async_copy16(src0 + zi * 256, slab16 + p * 1024 + h * 512);
        }
    }
    for (int i = t; i < 1728; i += 256) wl[i] = w2g[i];
    for (int row = w; row < 8; row += 4) {
        float v = wred(sp1[row * 64 + lane]);
        if (lane == 0) red[row] = v;
    }
    __syncthreads();
    if (t < 4) {
        float cnt = 4194304.0f;
        float m = red[2 * t] / cnt;
        float var = red[2 * t + 1] / cnt - m * m;
        float a = g1[t] * rsqrtf(var + BN_EPS);
        adl[t] = a; adl[4 + t] = be1[t] - m * a;
    }
    asm volatile("s_waitcnt vmcnt(0)" ::: "memory");
    __syncthreads();
    int zp = w >> 1;
    int cgo = __builtin_amdgcn_readfirstlane((w & 1) * 8);
    int yo = lane >> 3, xo = lane & 7;
    float my0 = yo ? 1.f : 0.f, mx0 = xo ? 1.f : 0.f;
    float mzw = (q == 0 && zp == 0) ? 0.f : 1.f;
    int yw3[3], sw3[3], xh3[3], xp3[3];
#pragma unroll
    for (int k = 0; k < 3; k++) {
        int yi = 2 * yo + k - 1; int yc = yi < 0 ? 0 : yi;
        yw3[k] = yc * 8;
        sw3[k] = ((yc >> 2) & 3) << 3;
        int xi = 2 * xo + k - 1; int xv = xi < 0 ? 0 : xi;
        xh3[k] = xv >> 1; xp3[k] = xv & 1;
    }
    float aa[4], dd[4];
#pragma unroll
    for (int c = 0; c < 4; c++) { aa[c] = adl[c]; dd[c] = adl[4 + c]; }
    float acc0[8], acc1[8];
#pragma unroll
    for (int c = 0; c < 8; c++) { acc0[c] = b2[cgo + c]; acc1[c] = acc0[c]; }
    for (int ci = 0; ci < 4; ci++) {
        float a = aa[ci], d = dd[ci];
        const unsigned short* pb16 = slab16 + zp * 4096 + ci * 256;
        const float* wci = wl + ci * 432 + cgo;
#pragma unroll
        for (int kz = 0; kz < 3; kz++) {
            const unsigned short* pl = pb16 + kz * 1024;
#pragma unroll
            for (int ky = 0; ky < 3; ky++) {
                int wb = yw3[ky], sw = sw3[ky];
#pragma unroll
                for (int kx = 0; kx < 3; kx++) {
                    int idx = (((wb + xh3[kx]) ^ sw) << 1) | xp3[kx];
                    float v0 = bf2f(pl[idx]);
                    float v1 = bf2f(pl[idx + 2048]);
                    float vb0 = fmaxf(a * v0 + d, 0.f);
                    float vb1 = fmaxf(a * v1 + d, 0.f);
                    if (kz == 0) vb0 *= mzw;
                    if (ky == 0) { vb0 *= my0; vb1 *= my0; }
                    if (kx == 0) { vb0 *= mx0; vb1 *= mx0; }
                    const float* wt = wci + (kz * 9 + ky * 3 + kx) * 16;
                    float4 wA = *(const float4*)(wt);
                    float4 wB = *(const float4*)(wt + 4);
                    acc0[0] += vb0 * wA.x; acc0[1] += vb0 * wA.y;
                    acc0[2] += vb0 * wA.z; acc0[3] += vb0 * wA.w;
                    acc0[4] += vb0 * wB.x; acc0[5] += vb0 * wB.y;
                    acc0[6] += vb0 * wB.z; acc0[7] += vb0 * wB.w;
                    acc1[0] += vb1 * wA.x; acc1[1] += vb1 * wA.y;
                    acc1[2] += vb1 * wA.z; acc1[3] += vb1 * wA.w;
                    acc1[4] += vb1 * wB.x; acc1[5] += vb1 * wB.y;
                    acc1[6] += vb1 * wB.z; acc1[7] += vb1 * wB.w;
                }
            }
        }
    }
    int z0 = 4 * q + 2 * zp;
    size_t ob = (size_t)b * 8192 + (size_t)cgo * 512 + z0 * 64 + lane;
#pragma unroll
    for (int c = 0; c < 8; c++) {
        y2[ob + c * 512] = acc0[c];
        y2[ob + c * 512 + 64] = acc1[c];
    }
    int slot = bid & 63;
#pragma unroll
    for (int c = 0; c < 8; c++) {
        float s_ = wred(acc0[c] + acc1[c]);
        float q_ = wred(acc0[c] * acc0[c] + acc1[c] * acc1[c]);
        if (lane == 0) {
            atomicAdd(&sp2[(2 * (cgo + c)) * 64 + slot], s_);
            atomicAdd(&sp2[(2 * (cgo + c) + 1) * 64 + slot], q_);
        }
    }
}

// ---------------- conv3: round-9 version (fp32 slab, uniform s_load weights) ----------------
__global__ __launch_bounds__(256) void k_c3(const float* __restrict__ y2,
                                            const float* __restrict__ w3g,
                                            const float* __restrict__ b3,
                                            const float* __restrict__ g2,
                                            const float* __restrict__ be2,
                                            const float* __restrict__ sp2,
                                            float* __restrict__ y3,
                                            float* __restrict__ sp3) {
    __shared__ __align__(16) float in3[8192];    // [16ci][512 swz] raw y2 sample
    __shared__ float adl[32], red[32];
    int t = threadIdx.x;
    int b = blockIdx.x;
    int w = t >> 6, lane = t & 63;
    int wu = __builtin_amdgcn_readfirstlane(w);
    const float* yb = y2 + (size_t)b * 8192;
    for (int j = 0; j < 8; j++) {
        int s = ((j << 2) + (lane >> 4)) & 7;
        async_copy16(yb + wu * 2048 + j * 256 + ((lane ^ s) << 2),
                     in3 + wu * 2048 + j * 256);
    }
    for (int row = w; row < 32; row += 4) {
        float v = wred(sp2[row * 64 + lane]);
        if (lane == 0) red[row] = v;
    }
    __syncthreads();
    if (t < 16) {
        float cnt = 524288.0f;
        float m = red[2 * t] / cnt;
        float var = red[2 * t + 1] / cnt - m * m;
        float a = g2[t] * rsqrtf(var + BN_EPS);
        adl[t] = a; adl[16 + t] = be2[t] - m * a;
    }
    asm volatile("s_waitcnt vmcnt(0)" ::: "memory");
    __syncthreads();
    int px = lane & 3, py = (lane >> 2) & 3, pz = lane >> 4;
    float mz0 = pz ? 1.f : 0.f, my0 = py ? 1.f : 0.f, mx0 = px ? 1.f : 0.f;
    int zb3[3], sz3[3], yv3[3], xv3[3];
#pragma unroll
    for (int k = 0; k < 3; k++) {
        int zi = 2 * pz + k - 1; int zc = zi < 0 ? 0 : zi;
        zb3[k] = zc * 64; sz3[k] = zc << 2;
        int yi = 2 * py + k - 1; int yc = yi < 0 ? 0 : yi;
        yv3[k] = yc * 8;
        int xi = 2 * px + k - 1; xv3[k] = xi < 0 ? 0 : xi;
    }
    int coh = wu & 1, cih = wu >> 1;
    int cgo = coh * 16;
    float acc[16];
#pragma unroll
    for (int c = 0; c < 16; c++) acc[c] = 0.f;
    for (int cii = 0; cii < 8; cii++) {
        int ci = cih * 8 + cii;
        float a = adl[ci], d = adl[16 + ci];
        const float* base = in3 + ci * 512;
        const float* wci = w3g + ci * 864 + cgo;
#pragma unroll
        for (int kz = 0; kz < 3; kz++) {
            int A1 = zb3[kz], sz = sz3[kz];
#pragma unroll
            for (int ky = 0; ky < 3; ky++) {
                int A2 = A1 + yv3[ky];
#pragma unroll
                for (int kx = 0; kx < 3; kx++) {
                    float v = base[(A2 + xv3[kx]) ^ sz];
                    float vb = fmaxf(a * v + d, 0.f);
                    if (kz == 0) vb *= mz0;
                    if (ky == 0) vb *= my0;
                    if (kx == 0) vb *= mx0;
                    const float* wr = wci + (kz * 9 + ky * 3 + kx) * 32;
#pragma unroll
                    for (int c = 0; c < 16; c++) acc[c] += vb * wr[c];
                }
            }
        }
    }
    __syncthreads();
    if (wu >= 2) {
        float* pp = in3 + (wu & 1) * 1280 + lane * 20;
#pragma unroll
        for (int c4 = 0; c4 < 4; c4++)
            *(float4*)(pp + c4 * 4) = make_float4(acc[c4*4], acc[c4*4+1], acc[c4*4+2], acc[c4*4+3]);
    }
    __syncthreads();
    if (wu < 2) {
        const float* pp = in3 + wu * 1280 + lane * 20;
#pragma unroll
        for (int c = 0; c < 16; c++) acc[c] += pp[c] + b3[cgo + c];
        size_t ob = (size_t)b * 2048 + lane;
#pragma unroll
        for (int c = 0; c < 16; c++) y3[ob + (size_t)(cgo + c) * 64] = acc[c];
        int slot = b & 63;
#pragma unroll
        for (int c = 0; c < 16; c++) {
            float s_ = wred(acc[c]), q_ = wred(acc[c] * acc[c]);
            if (lane == 0) {
                atomicAdd(&sp3[(2 * (cgo + c)) * 64 + slot], s_);
                atomicAdd(&sp3[(2 * (cgo + c) + 1) * 64 + slot], q_);
            }
        }
    }
}

// ---------------- conv4: round-9 version (fp32 slab, uniform s_load weights) ----------------
__global__ __launch_bounds__(256) void k_c4(const float* __restrict__ y3,
                                            const float* __restrict__ w4g,
                                            const float* __restrict__ b4,
                                            const float* __restrict__ g3,
                                            const float* __restrict__ be3,
                                            const float* __restrict__ sp3,
                                            float* __restrict__ y4,
                                            float* __restrict__ sp4) {
    __shared__ __align__(16) float in4[16416];   // 8 samples x 2052 (pad 4)
    __shared__ float adb[64], red[64];
    int t = threadIdx.x;
    int bid = blockIdx.x;
    int bq = bid >> 2, coq = bid & 3;
    int w = t >> 6, lane = t & 63;
    int wu = __builtin_amdgcn_readfirstlane(w);
#pragma unroll
    for (int h = 0; h < 2; h++) {
        int bs2 = wu * 2 + h;
        const float* src = y3 + (size_t)(bq * 8 + bs2) * 2048 + lane * 4;
        for (int j = 0; j < 8; j++)
            async_copy16(src + j * 256, in4 + bs2 * 2052 + j * 256);
    }
    for (int row = w; row < 64; row += 4) {
        float v = wred(sp3[row * 64 + lane]);
        if (lane == 0) red[row] = v;
    }
    __syncthreads();
    if (t < 32) {
        float cnt = 65536.0f;
        float m = red[2 * t] / cnt;
        float var = red[2 * t + 1] / cnt - m * m;
        float a = g3[t] * rsqrtf(var + BN_EPS);
        adb[t] = a; adb[32 + t] = be3[t] - m * a;
    }
    asm volatile("s_waitcnt vmcnt(0)" ::: "memory");
    __syncthreads();
    int bs = lane >> 3, pos = lane & 7;
    int pz = pos >> 2, py = (pos >> 1) & 1, px = pos & 1;
    int z0 = 2 * pz - 1; if (z0 < 0) z0 = 0;
    int y0 = 2 * py - 1; if (y0 < 0) y0 = 0;
    int x0 = 2 * px - 1; if (x0 < 0) x0 = 0;
    int zo_[3] = {z0 * 16, 2 * pz * 16, (2 * pz + 1) * 16};
    int yo_[3] = {y0 * 4, 2 * py * 4, (2 * py + 1) * 4};
    int xo_[3] = {x0, 2 * px, 2 * px + 1};
    float mz = pz ? 1.f : 0.f, my = py ? 1.f : 0.f, mx = px ? 1.f : 0.f;
    float acc[16];
#pragma unroll
    for (int c = 0; c < 16; c++) acc[c] = 0.f;
    const float* inb = in4 + bs * 2052;
    for (int cii = 0; cii < 8; cii++) {
        int ci = wu * 8 + cii;
        float a = adb[ci], d = adb[32 + ci];
        const float* inc = inb + ci * 64;
        const float* wcb = w4g + ci * 1728 + coq * 16;
#pragma unroll
        for (int kz = 0; kz < 3; kz++)
#pragma unroll
            for (int ky = 0; ky < 3; ky++)
#pragma unroll
                for (int kx = 0; kx < 3; kx++) {
                    float v = inc[zo_[kz] + yo_[ky] + xo_[kx]];
                    float vb = fmaxf(a * v + d, 0.f);
                    if (kz == 0) vb *= mz;
                    if (ky == 0) vb *= my;
                    if (kx == 0) vb *= mx;
                    const float* wr = wcb + (kz * 9 + ky * 3 + kx) * 64;
#pragma unroll
                    for (int c = 0; c < 16; c++) acc[c] += vb * wr[c];
                }
    }
    __syncthreads();
    if (wu > 0) {
        float* pp = in4 + (wu - 1) * 1280 + lane * 20;
#pragma unroll
        for (int c4 = 0; c4 < 4; c4++)
            *(float4*)(pp + c4 * 4) = make_float4(acc[c4*4], acc[c4*4+1], acc[c4*4+2], acc[c4*4+3]);
    }
    __syncthreads();
    if (wu == 0) {
#pragma unroll
        for (int p = 0; p < 3; p++) {
            const float* pp = in4 + p * 1280 + lane * 20;
#pragma unroll
            for (int c = 0; c < 16; c++) acc[c] += pp[c];
        }
        int bfull = bq * 8 + bs;
        size_t ob = (size_t)bfull * 512 + pos;
        int slot = bid & 63;
#pragma unroll
        for (int c = 0; c < 16; c++) {
            float vv = acc[c] + b4[coq * 16 + c];
            y4[ob + (size_t)(coq * 16 + c) * 8] = vv;
            acc[c] = vv;
        }
#pragma unroll
        for (int c = 0; c < 16; c++) {
            float s_ = wred(acc[c]), q_ = wred(acc[c] * acc[c]);
            if (lane == 0) {
                atomicAdd(&sp4[(2 * (coq * 16 + c)) * 64 + slot], s_);
                atomicAdd(&sp4[(2 * (coq * 16 + c) + 1) * 64 + slot], q_);
            }
        }
    }
}

// ---------------- conv5 as GEMM (unchanged) ----------------
__global__ __launch_bounds__(512) void k_c5(const float* __restrict__ y4,
                                            const float* __restrict__ w5g,
                                            const float* __restrict__ b5,
                                            const float* __restrict__ g4,
                                            const float* __restrict__ be4,
                                            const float* __restrict__ sp4,
                                            float* __restrict__ y5,
                                            float* __restrict__ sp5) {
    __shared__ __align__(16) float A[2048];
    __shared__ float P[512];
    __shared__ float ad[128], red[128];
    int t = threadIdx.x;
    int bq = blockIdx.x;
    int w = t >> 6, lane = t & 63;
    for (int row = w; row < 128; row += 8) {
        float v = wred(sp4[row * 64 + lane]);
        if (lane == 0) red[row] = v;
    }
    __syncthreads();
    if (t < 64) {
        float cnt = 8192.0f;
        float m = red[2 * t] / cnt;
        float var = red[2 * t + 1] / cnt - m * m;
        float a = g4[t] * rsqrtf(var + BN_EPS);
        ad[t] = a; ad[64 + t] = be4[t] - m * a;
    }
    __syncthreads();
    {
        int bs = t >> 7, k0 = (t & 127) << 2;
        float4 vv = *(const float4*)(y4 + (size_t)(bq * 4 + bs) * 512 + k0);
        int ci = k0 >> 3;
        float a = ad[ci], d = ad[64 + ci];
        float4 o;
        o.x = fmaxf(a * vv.x + d, 0.f);
        o.y = fmaxf(a * vv.y + d, 0.f);
        o.z = fmaxf(a * vv.z + d, 0.f);
        o.w = fmaxf(a * vv.w + d, 0.f);
        *(float4*)(A + bs * 512 + k0) = o;
    }
    __syncthreads();
    int bs = w & 3, kh = w >> 2;
    float acc0 = 0.f, acc1 = 0.f;
    const float* Ab = A + bs * 512 + kh * 256;
    const float* wp = w5g + kh * 32768 + lane * 2;
#pragma unroll 8
    for (int k = 0; k < 256; k++) {
        float2 wv = *(const float2*)(wp + k * 128);
        float av = Ab[k];
        acc0 += av * wv.x;
        acc1 += av * wv.y;
    }
    if (kh == 0) {
        P[bs * 128 + lane * 2] = acc0;
        P[bs * 128 + lane * 2 + 1] = acc1;
    }
    __syncthreads();
    if (kh == 1) {
        float f0 = acc0 + P[bs * 128 + lane * 2] + b5[lane * 2];
        float f1 = acc1 + P[bs * 128 + lane * 2 + 1] + b5[lane * 2 + 1];
        *(float2*)(y5 + (size_t)(bq * 4 + bs) * 128 + lane * 2) = make_float2(f0, f1);
        P[bs * 128 + lane * 2] = f0;
        P[bs * 128 + lane * 2 + 1] = f1;
    }
    __syncthreads();
    if (t < 128) {
        float s = 0.f, q = 0.f;
        for (int bb = 0; bb < 4; bb++) {
            float vv = P[bb * 128 + t];
            s += vv; q += vv * vv;
        }
        int slot = bq & 63;
        atomicAdd(&sp5[(2 * t) * 64 + slot], s);
        atomicAdd(&sp5[(2 * t + 1) * 64 + slot], q);
    }
}

// ---------------- final (unchanged) ----------------
__global__ __launch_bounds__(512) void k_f2(const float* __restrict__ s,
                                            const float* __restrict__ f2w,
                                            const float* __restrict__ f2b,
                                            const float* __restrict__ g5,
                                            const float* __restrict__ be5,
                                            const float* __restrict__ sp5,
                                            const float* __restrict__ y5,
                                            float* __restrict__ out) {
    __shared__ __align__(16) float A[2048];
    __shared__ float P[512];
    __shared__ float ad[256], red[256];
    int t = threadIdx.x;
    int bq = blockIdx.x;
    int w = t >> 6, lane = t & 63;
    for (int row = w; row < 256; row += 8) {
        float v = wred(sp5[row * 64 + lane]);
        if (lane == 0) red[row] = v;
    }
    __syncthreads();
    if (t < 128) {
        float cnt = 1024.0f;
        float m = red[2 * t] / cnt;
        float var = red[2 * t + 1] / cnt - m * m;
        float a = g5[t] * rsqrtf(var + BN_EPS);
        ad[t] = a; ad[128 + t] = be5[t] - m * a;
    }
    {
        int bs = t >> 7, k0 = (t & 127) << 2;
        float4 vv = *(const float4*)(s + (size_t)(bq * 4 + bs) * 512 + k0);
        *(float4*)(A + bs * 512 + k0) = vv;
    }
    __syncthreads();
    int bs = w & 3, kh = w >> 2;
    float acc0 = 0.f, acc1 = 0.f;
    const float* Ab = A + bs * 512 + kh * 256;
    const float* wp = f2w + kh * 32768 + lane * 2;
#pragma unroll 8
    for (int k = 0; k < 256; k++) {
        float2 wv = *(const float2*)(wp + k * 128);
        float av = Ab[k];
        acc0 += av * wv.x;
        acc1 += av * wv.y;
    }
    if (kh == 0) {
        P[bs * 128 + lane * 2] = acc0;
        P[bs * 128 + lane * 2 + 1] = acc1;
    }
    __syncthreads();
    if (kh == 1) {
        int b = bq * 4 + bs;
        int co = lane * 2;
        float2 vy = *(const float2*)(y5 + (size_t)b * 128 + co);
        float f0 = acc0 + P[bs * 128 + co] + f2b[co] +
                   fmaxf(ad[co] * vy.x + ad[128 + co], 0.f);
        float f1 = acc1 + P[bs * 128 + co + 1] + f2b[co + 1] +
                   fmaxf(ad[co + 1] * vy.y + ad[128 + co + 1], 0.f);
        *(float2*)(out + (size_t)b * 128 + co) = make_float2(f0, f1);
    }
}

extern "C" void kernel_launch(void* const* d_in, const int* in_sizes, int n_in,
                              void* d_out, int out_size, void* d_ws, size_t ws_size,
                              hipStream_t stream) {
    const float* vox     = (const float*)d_in[0];
    const float* centers = (const float*)d_in[1];
    const float* W1   = (const float*)d_in[2];
    const float* b1   = (const float*)d_in[3];
    const float* g1   = (const float*)d_in[4];
    const float* be1  = (const float*)d_in[5];
    const float* W2   = (const float*)d_in[6];
    const float* b2   = (const float*)d_in[7];
    const float* g2   = (const float*)d_in[8];
    const float* be2  = (const float*)d_in[9];
    const float* W3   = (const float*)d_in[10];
    const float* b3   = (const float*)d_in[11];
    const float* g3   = (const float*)d_in[12];
    const float* be3  = (const float*)d_in[13];
    const float* W4   = (const float*)d_in[14];
    const float* b4   = (const float*)d_in[15];
    const float* g4   = (const float*)d_in[16];
    const float* be4  = (const float*)d_in[17];
    const float* W5   = (const float*)d_in[18];
    const float* b5   = (const float*)d_in[19];
    const float* g5   = (const float*)d_in[20];
    const float* be5  = (const float*)d_in[21];
    const float* pe_w = (const float*)d_in[22];
    const float* pe_b = (const float*)d_in[23];
    const float* f1_w = (const float*)d_in[24];
    const float* f1_b = (const float*)d_in[25];
    const float* f2_w = (const float*)d_in[26];
    const float* f2_b = (const float*)d_in[27];

    float* ws  = (float*)d_ws;
    unsigned short* y1b = (unsigned short*)(ws + OFF_Y1);
    float* y2  = ws + OFF_Y2;
    float* y3  = ws + OFF_Y3;
    float* y4  = ws + OFF_Y4;
    float* y5  = ws + OFF_Y5;
    float* s   = ws + OFF_S;
    float* w2g = ws + OFF_W2G;
    float* w3g = ws + OFF_W3G;
    float* w4g = ws + OFF_W4G;
    float* w5g = ws + OFF_W5G;
    float* u   = ws + OFF_U;
    float* sp1 = ws + OFF_SP1;
    float* sp2 = ws + OFF_SP2;
    float* sp3 = ws + OFF_SP3;
    float* sp4 = ws + OFF_SP4;
    float* sp5 = ws + OFF_SP5;

    k_prep_w<<<439, 256, 0, stream>>>(W2, W3, W5, w2g, w3g, w5g, sp1);
    k_prep_u<<<1, 64, 0, stream>>>(pe_w, pe_b, f1_w, f1_b, u);
    k_pe<<<2048, 256, 0, stream>>>(centers, u, s);
    k_c1<<<2048, 256, 0, stream>>>(vox, W1, b1, y1b, sp1);
    k_c2<<<2048, 256, 0, stream>>>(y1b, w2g, b2, g1, be1, sp1, y2, sp2);
    k_prep_w4<<<216, 256, 0, stream>>>(W4, w4g);
    k_c3<<<1024, 256, 0, stream>>>(y2, w3g, b3, g2, be2, sp2, y3, sp3);
    k_c4<<<512, 256, 0, stream>>>(y3, w4g, b4, g3, be3, sp3, y4, sp4);
    k_c5<<<256, 512, 0, stream>>>(y4, w5g, b5, g4, be4, sp4, y5, sp5);
    k_f2<<<256, 512, 0, stream>>>(s, f2_w, f2_b, g5, be5, sp5, y5, (float*)d_out);
}